// Round 1
// baseline (813.307 us; speedup 1.0000x reference)
//
#include <hip/hip_runtime.h>

// LocalCorrelation: out[b, k=di*13+dj, h, w] =
//   (1/16) * sum_c z_t[b,c,h,w] * z_t1[b,c,h+di-6,w+dj-6]   (zero-padded)
// B=8 C=256 H=W=128, 13x13 taps.
//
// Block = one (b,h) output row, 256 threads.
//   compute: tid<208 -> r=tid/16 (di index 0..12), wg=tid%16 (w-group of 8)
//   each thread: 8w x 13dj register accumulators, loops all 256 channels
//   channels staged to LDS in chunks of 4 (z_t row + 13 padded z_t1 rows)
//   async-stage split: next chunk's global loads issued before compute.
// Grid swizzled so each XCD owns one batch b -> z_t1 row re-reads (13x) hit L2.

#define CC_TOT 256
#define HH 128
#define WW 128
#define RAD 6
#define KK 13
#define NTAP 169
#define CCH 4            // channels per LDS chunk
#define NCHUNK 64        // 256/4
#define S1 148           // z_t1 LDS row stride (floats): 8 pad + 128 data + 12 pad/align
#define S0 132           // z_t LDS row stride
#define LDS1 (CCH*KK*S1) // 7696 floats
#define LDS0 (CCH*S0)    // 528 floats
#define CHAN_STRIDE (HH*WW)      // 16384 floats per channel plane
#define CHUNK_ADV (CCH*HH*WW)    // advance per chunk (floats)

__global__ __launch_bounds__(256, 2)
void lc_kernel(const float* __restrict__ zt, const float* __restrict__ zt1,
               float* __restrict__ out) {
    __shared__ float s1[LDS1];
    __shared__ float s0[LDS0];

    const int bid = blockIdx.x;
    // XCD-aware swizzle: 1024 blocks, 8 XCDs -> XCD x gets batch b=x, h ascending.
    const int swz = (bid & 7) * 128 + (bid >> 3);
    const int b = swz >> 7;
    const int h = swz & 127;

    const int tid = threadIdx.x;

    // ---- zero LDS once (pads + out-of-range rows stay zero forever) ----
    for (int i = tid; i < LDS1; i += 256) s1[i] = 0.f;
    for (int i = tid; i < LDS0; i += 256) s0[i] = 0.f;

    // ---- staging descriptors (z_t1: 52 rows x 32 float4 = 1664 units) ----
    const float* src[7];
    int dst[7];
    bool ok[7];
#pragma unroll
    for (int u = 0; u < 7; ++u) {
        const int v = tid + u * 256;
        const bool inr = v < 1664;
        const int row = v >> 5;          // 0..51 = ch*13 + rr
        const int q   = v & 31;          // float4 index within row
        const int ch  = row / 13;
        const int rr  = row - ch * 13;   // di index
        const int hp  = h + rr - RAD;
        const bool val = inr && (hp >= 0) && (hp < HH);
        ok[u]  = val;
        dst[u] = (ch * KK + rr) * S1 + 8 + q * 4;
        src[u] = zt1 + ((b * CC_TOT + ch) * HH + (val ? hp : 0)) * WW + q * 4;
    }
    const int ch0 = tid >> 5, q0 = tid & 31;
    const bool ok0 = tid < 128;          // 4 ch x 32 float4 = 128 units
    const int dst0 = ch0 * S0 + q0 * 4;
    const float* src0 = zt + ((b * CC_TOT + ch0) * HH + h) * WW + q0 * 4;

    // ---- compute role ----
    const bool comp = tid < 208;
    const int r  = tid >> 4;             // di index 0..12
    const int wg = tid & 15;
    const int w0 = wg * 8;

    float acc[8][13];
#pragma unroll
    for (int wi = 0; wi < 8; ++wi)
#pragma unroll
        for (int dj = 0; dj < 13; ++dj) acc[wi][dj] = 0.f;

    // prefetch chunk 0 into registers (overlaps with LDS zero-init)
    float4 rg[7]; float4 rg0;
#pragma unroll
    for (int u = 0; u < 7; ++u) {
        if (ok[u]) rg[u] = *(const float4*)src[u];
        src[u] += CHUNK_ADV;
    }
    if (ok0) rg0 = *(const float4*)src0;
    src0 += CHUNK_ADV;

    __syncthreads();   // LDS zero-init complete

    for (int kc = 0; kc < NCHUNK; ++kc) {
        // write staged registers -> LDS
#pragma unroll
        for (int u = 0; u < 7; ++u)
            if (ok[u]) *(float4*)(&s1[dst[u]]) = rg[u];
        if (ok0) *(float4*)(&s0[dst0]) = rg0;

        // issue next chunk's global loads (latency hides under compute)
        if (kc + 1 < NCHUNK) {
#pragma unroll
            for (int u = 0; u < 7; ++u) {
                if (ok[u]) rg[u] = *(const float4*)src[u];
                src[u] += CHUNK_ADV;
            }
            if (ok0) rg0 = *(const float4*)src0;
            src0 += CHUNK_ADV;
        }

        __syncthreads();   // LDS writes visible

        if (comp) {
#pragma unroll
            for (int ch = 0; ch < CCH; ++ch) {
                union { float4 v4[6]; float f[24]; } zb;
                union { float4 v4[2]; float f[8];  } za;
                const float* p1 = &s1[(ch * KK + r) * S1 + w0];
#pragma unroll
                for (int t = 0; t < 6; ++t) zb.v4[t] = *(const float4*)(p1 + 4 * t);
                const float* p0 = &s0[ch * S0 + w0];
                za.v4[0] = *(const float4*)(p0);
                za.v4[1] = *(const float4*)(p0 + 4);
                // out w = w0+wi ; needs z_t1 at x = w0+wi+dj+2 (x=w_global+8)
#pragma unroll
                for (int wi = 0; wi < 8; ++wi)
#pragma unroll
                    for (int dj = 0; dj < 13; ++dj)
                        acc[wi][dj] = fmaf(za.f[wi], zb.f[wi + dj + 2], acc[wi][dj]);
            }
        }
        __syncthreads();   // compute done before next chunk overwrites LDS
    }

    if (comp) {
        const float sc = 0.0625f;  // 1/sqrt(256)
#pragma unroll
        for (int dj = 0; dj < 13; ++dj) {
            const int k = r * 13 + dj;
            float* po = out + ((b * NTAP + k) * HH + h) * WW + w0;
            float4 o0 = make_float4(acc[0][dj] * sc, acc[1][dj] * sc,
                                    acc[2][dj] * sc, acc[3][dj] * sc);
            float4 o1 = make_float4(acc[4][dj] * sc, acc[5][dj] * sc,
                                    acc[6][dj] * sc, acc[7][dj] * sc);
            *(float4*)po = o0;
            *(float4*)(po + 4) = o1;
        }
    }
}

extern "C" void kernel_launch(void* const* d_in, const int* in_sizes, int n_in,
                              void* d_out, int out_size, void* d_ws, size_t ws_size,
                              hipStream_t stream) {
    const float* zt  = (const float*)d_in[0];
    const float* zt1 = (const float*)d_in[1];
    float* out = (float*)d_out;
    lc_kernel<<<dim3(1024), dim3(256), 0, stream>>>(zt, zt1, out);
}

// Round 2
// 143.515 us; speedup vs baseline: 5.6671x; 5.6671x over previous
//
#include <hip/hip_runtime.h>
#include <hip/hip_bf16.h>

// LocalCorrelation via MFMA pixel-pair dot products.
// out[b, di*13+dj, h, w] = (1/16) * sum_c zt[b,c,h,w] * zt1[b,c,h+di-6,w+dj-6]
// B=8 C=256 H=W=128, 13x13 taps, zero-padded.
//
// D[m,n] = sum_c A[c, p_m] * B[c, q_n]  == mfma_f32_16x16x32_bf16
//   (M = 16 zt pixels of a 4x4 patch, N = 16 zt1 pixels of a 4x4 patch, K = 32 ch)
// Each p-patch pairs with 16 q-patches on a 4-grid offset by (-6,-6);
// 66% of D entries are valid (di,dj) outputs (52^2 = 2704 = 16*169 exactly).
//
// Block: 512 thr = 8 waves, p-region 8h x 16w (wave w -> p-patch (w>>2, w&3)).
// K-loop: 8 chunks of 32 ch; fp32->bf16 transposed staging to LDS [pix][c],
// T14 register prefetch of next chunk. Epilogue: two 85-k-plane passes staged
// through LDS (k-stride 132 vs bank conflicts) then coalesced float4 stores.

#define CC 256
#define HH 128
#define WW 128
#define NT 169
#define PH 8
#define PW 16
#define QH 20            // PH + 12
#define QW 28            // PW + 12
#define CCH 32           // channels per chunk
#define NCH 8            // 256/32
#define CS 40            // LDS channel-stride (bf16): 80B, 16B-aligned
#define NPIXB (QH*QW)    // 560
#define NPIXA (PH*PW)    // 128
#define NUB (NPIXB*4)    // 2240 zt1 units (8-channel octets)
#define NUNIT (NUB + NPIXA*4)  // 2752
#define UPT 6            // ceil(2752/512)
#define CHPLANE (HH*WW)  // 16384
#define ABYTE (NPIXB*CS*2)     // 44800: byte offset of A region in stage
#define KHALF 85
#define OSTRIDE 132      // out-stage k-plane stride (floats)

typedef __attribute__((ext_vector_type(8))) short bf16x8;
typedef __attribute__((ext_vector_type(4))) float f32x4;

union SMEM {
    unsigned short stage[NPIXB*CS + NPIXA*CS];   // B then A, 55040 B
    float outb[KHALF*OSTRIDE];                   // 44880 B
};

static __device__ __forceinline__ unsigned pk2(float a, float b) {
    unsigned x = __bfloat16_as_ushort(__float2bfloat16(a));
    unsigned y = __bfloat16_as_ushort(__float2bfloat16(b));
    return x | (y << 16);
}

__global__ __launch_bounds__(512, 2)
void lc_mfma(const float* __restrict__ zt, const float* __restrict__ zt1,
             float* __restrict__ out) {
    __shared__ SMEM sm;
    char* smb = (char*)&sm;

    const int tid  = threadIdx.x;
    const int lane = tid & 63;
    const int wid  = tid >> 6;            // 0..7
    const int py0  = (wid >> 2) * 4;      // p-patch origin in block
    const int px0  = (wid & 3) * 4;

    const int bid = blockIdx.x;
    const int b   = bid & 7;              // one batch per XCD
    const int t   = bid >> 3;             // 0..127
    const int h0  = (t >> 3) * PH;
    const int w0  = (t & 7) * PW;

    // ---- staging unit descriptors (constant across chunks) ----
    const float* src[UPT];
    int   dstB[UPT];
    bool  ex[UPT], pv[UPT];
#pragma unroll
    for (int v = 0; v < UPT; ++v) {
        const int ui = tid + v * 512;
        ex[v] = ui < NUNIT;
        int pix, oct, gy, gx, valid;
        const float* base;
        if (ui < NUB) {                       // zt1 unit
            oct = ui / NPIXB;
            pix = ui - oct * NPIXB;
            const int qyi = pix / QW;
            const int qxi = pix - qyi * QW;
            gy = h0 + qyi - 6;
            gx = w0 + qxi - 6;
            valid = (gy >= 0) & (gy < HH) & (gx >= 0) & (gx < WW);
            base = zt1;
            dstB[v] = pix * (CS*2) + oct * 16;
        } else {                              // zt unit
            const int u2 = ui - NUB;          // 0..511
            oct = u2 >> 7;
            pix = u2 & 127;
            gy = h0 + (pix >> 4);
            gx = w0 + (pix & 15);
            valid = 1;
            base = zt;
            dstB[v] = ABYTE + pix * (CS*2) + oct * 16;
        }
        pv[v] = valid;
        src[v] = base + (((b * CC + oct * 8) * HH + (valid ? gy : 0)) * WW + (valid ? gx : 0));
    }

    // ---- fragment LDS byte offsets (constant across chunks) ----
    const int nlo = lane & 3, nhi = (lane >> 2) & 3, oo = lane >> 4;
    int boff[16];
#pragma unroll
    for (int qi = 0; qi < 16; ++qi) {
        const int qyL = py0 + (qi >> 2) * 4 + nhi;   // 0..19
        const int qxL = px0 + (qi & 3) * 4 + nlo;    // 0..27
        boff[qi] = (qyL * QW + qxL) * (CS*2) + oo * 16;
    }
    const int pixA = (py0 + nhi) * PW + px0 + nlo;   // A-frag: m = lane&15
    const int aoff = ABYTE + pixA * (CS*2) + oo * 16;

    f32x4 acc[16];
#pragma unroll
    for (int qi = 0; qi < 16; ++qi) acc[qi] = (f32x4){0.f, 0.f, 0.f, 0.f};

    // ---- prefetch chunk 0 ----
    float pf[UPT][8];
#pragma unroll
    for (int v = 0; v < UPT; ++v) {
        const bool ld = ex[v] && pv[v];
#pragma unroll
        for (int j = 0; j < 8; ++j) pf[v][j] = ld ? src[v][j * CHPLANE] : 0.f;
        src[v] += CCH * CHPLANE;
    }

    for (int kc = 0; kc < NCH; ++kc) {
        // write staged regs -> LDS
#pragma unroll
        for (int v = 0; v < UPT; ++v) {
            if (ex[v]) {
                uint4 q;
                q.x = pk2(pf[v][0], pf[v][1]);
                q.y = pk2(pf[v][2], pf[v][3]);
                q.z = pk2(pf[v][4], pf[v][5]);
                q.w = pk2(pf[v][6], pf[v][7]);
                *(uint4*)(smb + dstB[v]) = q;
            }
        }
        // prefetch next chunk (global latency hides under MFMA phase)
        if (kc + 1 < NCH) {
#pragma unroll
            for (int v = 0; v < UPT; ++v) {
                const bool ld = ex[v] && pv[v];
#pragma unroll
                for (int j = 0; j < 8; ++j) pf[v][j] = ld ? src[v][j * CHPLANE] : 0.f;
                src[v] += CCH * CHPLANE;
            }
        }
        __syncthreads();   // staging visible

        const bf16x8 af = *(const bf16x8*)(smb + aoff);
#pragma unroll
        for (int qi = 0; qi < 16; ++qi) {
            const bf16x8 bfr = *(const bf16x8*)(smb + boff[qi]);
            acc[qi] = __builtin_amdgcn_mfma_f32_16x16x32_bf16(af, bfr, acc[qi], 0, 0, 0);
        }
        __syncthreads();   // compute done before next overwrite
    }

    // ---- epilogue: two passes through LDS for coalesced stores ----
    // C/D layout: n = lane&15, m = (lane>>4)*4 + reg  ->  py=py0+oo, px=px0+reg
    const int psb = (py0 + oo) * PW + px0;
#pragma unroll 1
    for (int pass = 0; pass < 2; ++pass) {
        const int kb = pass * KHALF;
        const int nk = pass ? (NT - KHALF) : KHALF;   // 85 / 84
#pragma unroll
        for (int qi = 0; qi < 16; ++qi) {
            const int di = 4 * (qi >> 2) + nhi - oo;
            const bool diok = (unsigned)di <= 12u;
            const int dib = di * 13;
#pragma unroll
            for (int r = 0; r < 4; ++r) {
                const int dj = 4 * (qi & 3) + nlo - r;
                const int k  = dib + dj;
                if (diok && (unsigned)dj <= 12u && k >= kb && k < kb + nk)
                    sm.outb[(k - kb) * OSTRIDE + psb + r] = acc[qi][r] * 0.0625f;
            }
        }
        __syncthreads();
        const int total4 = nk * 32;
        for (int i = tid; i < total4; i += 512) {
            const int row = i >> 5, j = i & 31;
            const float4 val = *(const float4*)&sm.outb[row * OSTRIDE + j * 4];
            float* dst = out + (((b * NT + kb + row) * HH + h0 + (j >> 2)) * WW
                                + w0 + (j & 3) * 4);
            *(float4*)dst = val;
        }
        __syncthreads();
    }
}

extern "C" void kernel_launch(void* const* d_in, const int* in_sizes, int n_in,
                              void* d_out, int out_size, void* d_ws, size_t ws_size,
                              hipStream_t stream) {
    const float* zt  = (const float*)d_in[0];
    const float* zt1 = (const float*)d_in[1];
    float* out = (float*)d_out;
    lc_mfma<<<dim3(1024), dim3(512), 0, stream>>>(zt, zt1, out);
}